// Round 1
// baseline (4382.640 us; speedup 1.0000x reference)
//
#include <hip/hip_runtime.h>
#include <hip/hip_bf16.h>
#include <math.h>

// GPT blocks: B=4, T=2048, C=1024, FF=4096, NB=8. Single-head causal attn.
// GEMM: 256x256 tile, BK=64, 8 waves (2Mx4N), 4-phase-per-K-tile schedule
// (HK-style T2 swizzle + T3/T4 counted-vmcnt pipeline + T5 setprio + T1 XCD
// remap). LDS 128KB double-buffered; global_load_lds width-16 staging with
// XOR bank-swizzle applied on the global source address.

typedef __bf16 bf16;
typedef __bf16 bf16x8 __attribute__((ext_vector_type(8)));
typedef __bf16 bf16x4 __attribute__((ext_vector_type(4)));
typedef float f32x4 __attribute__((ext_vector_type(4)));

#define BM 256
#define BN 256
#define BK 64

__device__ __forceinline__ void async_load16(const void* g, void* l) {
  __builtin_amdgcn_global_load_lds(
      (const __attribute__((address_space(1))) void*)g,
      (__attribute__((address_space(3))) void*)l, 16, 0, 0);
}

// raw s_barrier with compiler memory fences (no vmcnt/lgkm drain at HW level;
// the fences stop IR-level motion of LDS ops across the barrier).
__device__ __forceinline__ void barrier_fence() {
  asm volatile("" ::: "memory");
  __builtin_amdgcn_s_barrier();
  asm volatile("" ::: "memory");
}

constexpr int EPI_BF16 = 0;     // C = bf16(acc + bias)           (bias may be null)
constexpr int EPI_GELU = 1;     // C = bf16(gelu(acc + bias))
constexpr int EPI_RESID = 2;    // C = f32(resid + acc + bias)
constexpr int EPI_F32SCALE = 3; // C = f32(acc * alpha)

// Stage one 128x64 half-tile: 2 x global_load_lds(16B) per thread.
// LDS dest is lane-linear (HW adds lane*16B); source address carries the
// XOR k-granule swizzle (S0/S1 already include row0 and q0).
#define STAGE(S0, S1, LB, HH, JJ, LD)                                \
  do {                                                               \
    const long soff_ = (long)(HH)*128 * (LD) + (long)(JJ)*64;        \
    async_load16((S0) + soff_, (LB) + (HH)*8192);                    \
    async_load16((S1) + soff_, (LB) + (HH)*8192 + 4096);             \
  } while (0)

// C[M,N] = A[M,K] @ B[N,K]^T ; tiles full (M,N mult of 256, K mult of 64).
// gridDim.y (m-strips) must be a multiple of 8 for the XCD remap.
template <int EPI>
__global__ __launch_bounds__(512, 2) void gemm_bt(
    const bf16* __restrict__ A, const bf16* __restrict__ Bw,
    const float* __restrict__ bias, const float* __restrict__ resid,
    void* __restrict__ Cout, int K, int lda, int ldb, int ldc,
    long batchA, long batchB, long batchC, float alpha,
    int causalSkip, int kLimit) {
  // --- XCD-aware remap: each XCD owns whole m-strips (A reuse in its L2).
  const int nx = gridDim.x;
  const int lin = blockIdx.y * nx + blockIdx.x;
  const int xcd = lin & 7;
  const int tt = lin >> 3;
  const int n_idx = tt % nx;
  const int j_idx = tt / nx;
  const int m0 = (xcd + 8 * j_idx) * BM;
  const int n0 = n_idx * BN;
  if (causalSkip && n0 > m0) return;  // fully-masked score tile
  const int bz = blockIdx.z;
  const bf16* Ab = A + (long)bz * batchA;
  const bf16* Bb = Bw + (long)bz * batchB;
  const int kEnd = kLimit ? ((m0 + BM < K) ? (m0 + BM) : K) : K;
  const int nT = kEnd >> 6;  // K-tiles of 64 (always >= 4 here)

  // [buf:2][mat A/B:2][half:2][128 rows][64 k] bf16 = 128 KiB
  __shared__ alignas(16) bf16 sm[65536];

  const int tid = threadIdx.x;
  const int wave = tid >> 6;
  const int lane = tid & 63;
  const int wr = wave >> 2;  // 2 m-wave rows (128 rows each)
  const int wc = wave & 3;   // 4 n-wave cols (64 cols each)
  const int l16 = lane & 15;
  const int kq = lane >> 4;

  // --- staging geometry: granule g = rep*512 + tid covers row g>>3 (0..127),
  // physical k-granule p = g&7. Bank swizzle: physical p holds logical
  // q = p ^ (row&7), applied on the GLOBAL source (LDS write is lane-linear).
  const int row0 = tid >> 3;                       // 0..63 (rep adds 64)
  const int q0 = (tid & 7) ^ ((tid >> 3) & 7);
  const bf16* aS0 = Ab + (long)(m0 + row0) * lda + q0 * 8;
  const bf16* aS1 = aS0 + (long)64 * lda;
  const bf16* bS0 = Bb + (long)(n0 + row0) * ldb + q0 * 8;
  const bf16* bS1 = bS0 + (long)64 * ldb;
  bf16* ldsA = sm + wave * 512;           // + buf*32768 + h*8192 + rep*4096
  bf16* ldsB = sm + 16384 + wave * 512;

  // --- fragment ds_read offsets: logical granule (ks*4+kq) at row r lives at
  // physical granule (ks*4+kq)^(r&7); fragment rows = 16*mi + l16 -> r&7=l16&7.
  int xk[2];
  xk[0] = ((0 + kq) ^ (l16 & 7)) * 8;
  xk[1] = ((4 + kq) ^ (l16 & 7)) * 8;
  const int aBase = wr * 8192 + l16 * 64;                            // A half
  const int bBase = 16384 + (wc >> 1) * 8192 + (wc & 1) * 4096 + l16 * 64;

  f32x4 acc[8][4] = {};
  bf16x8 a0[4][2], a1[4][2], b01[2][2], b23[2][2];

  // --- prologue: tile0 all 4 halves + tile1 A halves (6 half-tiles, 12 loads)
  STAGE(aS0, aS1, ldsA, 0, 0, lda);
  STAGE(aS0, aS1, ldsA, 1, 0, lda);
  STAGE(bS0, bS1, ldsB, 0, 0, ldb);
  STAGE(bS0, bS1, ldsB, 1, 0, ldb);
  STAGE(aS0, aS1, ldsA + 32768, 0, 1, lda);
  STAGE(aS0, aS1, ldsA + 32768, 1, 1, lda);
  asm volatile("s_waitcnt vmcnt(4)" ::: "memory");  // tile0 landed; tile1 A in flight
  barrier_fence();

  for (int t = 0; t < nT; ++t) {
    const int b = t & 1;
    const int aOff = b * 32768 + aBase;
    const int bOff = b * 32768 + bBase;
    bf16* sBn = ldsB + (b ^ 1) * 32768;  // B of tile t+1 (other buffer)
    bf16* sAc = ldsA + b * 32768;        // A of tile t+2 (this buffer)

    // ---- P1: read A[0..3],B[0..1] of tile t; stage B-half0(t+1)
#pragma unroll
    for (int mi = 0; mi < 4; ++mi)
#pragma unroll
      for (int ks = 0; ks < 2; ++ks)
        a0[mi][ks] = *(const bf16x8*)(sm + aOff + mi * 1024 + xk[ks]);
#pragma unroll
    for (int ni = 0; ni < 2; ++ni)
#pragma unroll
      for (int ks = 0; ks < 2; ++ks)
        b01[ni][ks] = *(const bf16x8*)(sm + bOff + ni * 1024 + xk[ks]);
    if (t + 1 < nT) STAGE(bS0, bS1, sBn, 0, t + 1, ldb);
    barrier_fence();
    asm volatile("s_waitcnt lgkmcnt(0)" ::: "memory");
    __builtin_amdgcn_s_setprio(1);
#pragma unroll
    for (int mi = 0; mi < 4; ++mi)
#pragma unroll
      for (int ni = 0; ni < 2; ++ni)
#pragma unroll
        for (int ks = 0; ks < 2; ++ks)
          acc[mi][ni] = __builtin_amdgcn_mfma_f32_16x16x32_bf16(
              a0[mi][ks], b01[ni][ks], acc[mi][ni], 0, 0, 0);
    __builtin_amdgcn_s_setprio(0);
    barrier_fence();

    // ---- P2: read A[4..7],B[2..3]; stage B-half1(t+1)
#pragma unroll
    for (int mi = 0; mi < 4; ++mi)
#pragma unroll
      for (int ks = 0; ks < 2; ++ks)
        a1[mi][ks] = *(const bf16x8*)(sm + aOff + (mi + 4) * 1024 + xk[ks]);
#pragma unroll
    for (int ni = 0; ni < 2; ++ni)
#pragma unroll
      for (int ks = 0; ks < 2; ++ks)
        b23[ni][ks] = *(const bf16x8*)(sm + bOff + (ni + 2) * 1024 + xk[ks]);
    if (t + 1 < nT) STAGE(bS0, bS1, sBn, 1, t + 1, ldb);
    barrier_fence();
    asm volatile("s_waitcnt lgkmcnt(0)" ::: "memory");
    __builtin_amdgcn_s_setprio(1);
#pragma unroll
    for (int mi = 0; mi < 4; ++mi)
#pragma unroll
      for (int ni = 0; ni < 2; ++ni)
#pragma unroll
        for (int ks = 0; ks < 2; ++ks)
          acc[mi][ni + 2] = __builtin_amdgcn_mfma_f32_16x16x32_bf16(
              a0[mi][ks], b23[ni][ks], acc[mi][ni + 2], 0, 0, 0);
    __builtin_amdgcn_s_setprio(0);
    barrier_fence();

    // ---- P3: stage A-half0(t+2) (buf-b A reads all completed at P2)
    if (t + 2 < nT) STAGE(aS0, aS1, sAc, 0, t + 2, lda);
    barrier_fence();
    __builtin_amdgcn_s_setprio(1);
#pragma unroll
    for (int mi = 0; mi < 4; ++mi)
#pragma unroll
      for (int ni = 0; ni < 2; ++ni)
#pragma unroll
        for (int ks = 0; ks < 2; ++ks)
          acc[mi + 4][ni + 2] = __builtin_amdgcn_mfma_f32_16x16x32_bf16(
              a1[mi][ks], b23[ni][ks], acc[mi + 4][ni + 2], 0, 0, 0);
    __builtin_amdgcn_s_setprio(0);
    barrier_fence();

    // ---- P4: stage A-half1(t+2); counted vmcnt (tile t+1 landed, 2
    // half-tiles of t+2 stay in flight across the barrier)
    if (t + 2 < nT) {
      STAGE(aS0, aS1, sAc, 1, t + 2, lda);
      asm volatile("s_waitcnt vmcnt(4)" ::: "memory");
    } else if (t + 1 < nT) {
      asm volatile("s_waitcnt vmcnt(0)" ::: "memory");  // tail drain (once)
    }
    barrier_fence();
    __builtin_amdgcn_s_setprio(1);
#pragma unroll
    for (int mi = 0; mi < 4; ++mi)
#pragma unroll
      for (int ni = 0; ni < 2; ++ni)
#pragma unroll
        for (int ks = 0; ks < 2; ++ks)
          acc[mi + 4][ni] = __builtin_amdgcn_mfma_f32_16x16x32_bf16(
              a1[mi][ks], b01[ni][ks], acc[mi + 4][ni], 0, 0, 0);
    __builtin_amdgcn_s_setprio(0);
    barrier_fence();
  }

  // C/D layout: col = lane&15, row = (lane>>4)*4 + reg  [m89/m91 verified]
  const int baseRow = m0 + wr * 128 + (lane >> 4) * 4;
  const int baseCol = n0 + wc * 64 + l16;
#pragma unroll
  for (int ni = 0; ni < 4; ++ni) {
    const int col = baseCol + ni * 16;
    float bv = 0.0f;
    if (EPI != EPI_F32SCALE && bias != nullptr) bv = bias[col];
#pragma unroll
    for (int mi = 0; mi < 8; ++mi) {
      const int rowb = baseRow + mi * 16;
#pragma unroll
      for (int r = 0; r < 4; ++r) {
        const float v = acc[mi][ni][r];
        const long idx = (long)bz * batchC + (long)(rowb + r) * ldc + col;
        if (EPI == EPI_F32SCALE) {
          ((float*)Cout)[idx] = v * alpha;
        } else if (EPI == EPI_RESID) {
          ((float*)Cout)[idx] = resid[idx] + v + bv;
        } else if (EPI == EPI_GELU) {
          const float u = v + bv;
          const float g = 0.5f * u * (1.0f + erff(u * 0.70710678118654752f));
          ((bf16*)Cout)[idx] = (bf16)g;
        } else {
          ((bf16*)Cout)[idx] = (bf16)(v + bv);
        }
      }
    }
  }
}

// LayerNorm: one block per row of 1024, fp32 in -> bf16 out
__global__ __launch_bounds__(256) void ln_kernel(
    const float* __restrict__ x, const float* __restrict__ w,
    const float* __restrict__ b, bf16* __restrict__ out) {
  const int C = 1024;
  const long row = blockIdx.x;
  const int t = threadIdx.x;
  const float4 v = ((const float4*)(x + row * C))[t];
  float s = v.x + v.y + v.z + v.w;
  float sq = v.x * v.x + v.y * v.y + v.z * v.z + v.w * v.w;
#pragma unroll
  for (int o = 1; o < 64; o <<= 1) {
    s += __shfl_xor(s, o, 64);
    sq += __shfl_xor(sq, o, 64);
  }
  __shared__ float rs[4], rq[4];
  const int wv = t >> 6, ln = t & 63;
  if (!ln) { rs[wv] = s; rq[wv] = sq; }
  __syncthreads();
  s = rs[0] + rs[1] + rs[2] + rs[3];
  sq = rq[0] + rq[1] + rq[2] + rq[3];
  const float mean = s * (1.0f / 1024.0f);
  const float var = sq * (1.0f / 1024.0f) - mean * mean;
  const float rstd = rsqrtf(var + 1e-5f);
  const float4 wv4 = ((const float4*)w)[t];
  const float4 bv4 = ((const float4*)b)[t];
  bf16x4 o = {(bf16)((v.x - mean) * rstd * wv4.x + bv4.x),
              (bf16)((v.y - mean) * rstd * wv4.y + bv4.y),
              (bf16)((v.z - mean) * rstd * wv4.z + bv4.z),
              (bf16)((v.w - mean) * rstd * wv4.w + bv4.w)};
  ((bf16x4*)(out + row * C))[t] = o;
}

// Causal softmax over fp32 scores row (already scaled) -> bf16 P, zeros for s>t
__global__ __launch_bounds__(256) void softmax_causal(
    const float* __restrict__ S, bf16* __restrict__ P) {
  const int T = 2048;
  const int t = blockIdx.x, b = blockIdx.y;
  const long rowoff = ((long)b * T + t) * (long)T;
  const float* row = S + rowoff;
  bf16* prow = P + rowoff;
  const int L = t + 1;
  const int tid = threadIdx.x;
  float vals[8];
  float mx = -1e30f;
#pragma unroll
  for (int i = 0; i < 8; i++) {
    const int idx = tid + i * 256;
    if (idx < L) {
      vals[i] = row[idx];
      mx = fmaxf(mx, vals[i]);
    } else {
      vals[i] = -1e30f;
    }
  }
#pragma unroll
  for (int o = 1; o < 64; o <<= 1) mx = fmaxf(mx, __shfl_xor(mx, o, 64));
  __shared__ float red[4], red2[4];
  const int wv = tid >> 6, ln = tid & 63;
  if (!ln) red[wv] = mx;
  __syncthreads();
  mx = fmaxf(fmaxf(red[0], red[1]), fmaxf(red[2], red[3]));
  float sum = 0.0f;
#pragma unroll
  for (int i = 0; i < 8; i++) {
    const int idx = tid + i * 256;
    const float e = (idx < L) ? __expf(vals[i] - mx) : 0.0f;
    vals[i] = e;
    sum += e;
  }
#pragma unroll
  for (int o = 1; o < 64; o <<= 1) sum += __shfl_xor(sum, o, 64);
  if (!ln) red2[wv] = sum;
  __syncthreads();
  sum = red2[0] + red2[1] + red2[2] + red2[3];
  const float inv = 1.0f / sum;
#pragma unroll
  for (int i = 0; i < 8; i++) prow[tid + i * 256] = (bf16)(vals[i] * inv);
}

// V transpose: qkv[b, s, 2048+c] -> vt[b, c, s]  (bf16)
__global__ __launch_bounds__(256) void transpose_v(
    const bf16* __restrict__ qkv, bf16* __restrict__ vt) {
  const int T = 2048, C3 = 3072, C = 1024, COFF = 2048;
  __shared__ bf16 tile[32][33];
  const int b = blockIdx.z;
  const int s0 = blockIdx.x * 32, c0 = blockIdx.y * 32;
  const int tx = threadIdx.x & 31, ty0 = threadIdx.x >> 5;
#pragma unroll
  for (int j = 0; j < 4; j++) {
    const int ty = ty0 + j * 8;
    tile[ty][tx] = qkv[((long)b * T + s0 + ty) * C3 + COFF + c0 + tx];
  }
  __syncthreads();
#pragma unroll
  for (int j = 0; j < 4; j++) {
    const int ty = ty0 + j * 8;
    vt[(long)b * C * T + (long)(c0 + ty) * T + s0 + tx] = tile[tx][ty];
  }
}

__global__ void f2bf_kernel(const float* __restrict__ in,
                            bf16* __restrict__ out, long n4) {
  const long i = (long)blockIdx.x * blockDim.x + threadIdx.x;
  if (i < n4) {
    const float4 v = ((const float4*)in)[i];
    bf16x4 o = {(bf16)v.x, (bf16)v.y, (bf16)v.z, (bf16)v.w};
    ((bf16x4*)out)[i] = o;
  }
}

extern "C" void kernel_launch(void* const* d_in, const int* in_sizes, int n_in,
                              void* d_out, int out_size, void* d_ws,
                              size_t ws_size, hipStream_t stream) {
  const int Bb = 4, T = 2048, C = 1024, FF = 4096, NB = 8;
  const int M = Bb * T;  // 8192
  const float* x_in = (const float*)d_in[0];
  const float* ln1_w = (const float*)d_in[1];
  const float* ln1_b = (const float*)d_in[2];
  const float* qkv_w = (const float*)d_in[3];
  const float* qkv_b = (const float*)d_in[4];
  const float* out_w = (const float*)d_in[5];
  const float* out_b = (const float*)d_in[6];
  const float* ln2_w = (const float*)d_in[7];
  const float* ln2_b = (const float*)d_in[8];
  const float* ff0_w = (const float*)d_in[9];
  const float* ff0_b = (const float*)d_in[10];
  const float* ff3_w = (const float*)d_in[11];
  const float* ff3_b = (const float*)d_in[12];
  float* x = (float*)d_out;  // fp32 residual stream lives in d_out

  char* p = (char*)d_ws;
  auto alloc = [&](size_t bytes) {
    char* r = p;
    p += (bytes + 255) & ~(size_t)255;
    return r;
  };
  bf16* wqkv = (bf16*)alloc((size_t)NB * 3 * C * C * 2);
  bf16* wout = (bf16*)alloc((size_t)NB * C * C * 2);
  bf16* wff0 = (bf16*)alloc((size_t)NB * FF * C * 2);
  bf16* wff3 = (bf16*)alloc((size_t)NB * C * FF * 2);
  bf16* hbuf = (bf16*)alloc((size_t)M * C * 2);
  bf16* qkvb = (bf16*)alloc((size_t)M * 3 * C * 2);
  float* att = (float*)alloc((size_t)Bb * T * T * 4);
  bf16* pbuf = (bf16*)alloc((size_t)Bb * T * T * 2);
  bf16* vt = (bf16*)alloc((size_t)Bb * C * T * 2);
  bf16* aout = (bf16*)alloc((size_t)M * C * 2);
  bf16* ffb = (bf16*)att;  // FF intermediate aliases scores buffer (phase-disjoint)

  auto conv = [&](const float* src, bf16* dst, long n) {
    const long n4 = n / 4;
    f2bf_kernel<<<dim3((unsigned)((n4 + 255) / 256)), dim3(256), 0, stream>>>(
        src, dst, n4);
  };
  conv(qkv_w, wqkv, (long)NB * 3 * C * C);
  conv(out_w, wout, (long)NB * C * C);
  conv(ff0_w, wff0, (long)NB * FF * C);
  conv(ff3_w, wff3, (long)NB * C * FF);

  hipMemcpyAsync(x, x_in, (size_t)M * C * 4, hipMemcpyDeviceToDevice, stream);

  const float scale = 1.0f / 32.0f;  // 1/sqrt(C)

  for (int blk = 0; blk < NB; blk++) {
    const bf16* wq = wqkv + (long)blk * 3 * C * C;
    const bf16* wo = wout + (long)blk * C * C;
    const bf16* w0 = wff0 + (long)blk * FF * C;
    const bf16* w3 = wff3 + (long)blk * C * FF;
    const float* l1w = ln1_w + blk * C;
    const float* l1b = ln1_b + blk * C;
    const float* l2w = ln2_w + blk * C;
    const float* l2b = ln2_b + blk * C;
    const float* qb = qkv_b + blk * 3 * C;
    const float* ob = out_b + blk * C;
    const float* f0b = ff0_b + blk * FF;
    const float* f3b = ff3_b + blk * C;

    // h = LN1(x)
    ln_kernel<<<dim3(M), dim3(256), 0, stream>>>(x, l1w, l1b, hbuf);
    // qkv = h @ Wqkv^T + b
    gemm_bt<EPI_BF16><<<dim3(3 * C / BN, M / BM), dim3(512), 0, stream>>>(
        hbuf, wq, qb, nullptr, qkvb, C, C, C, 3 * C, 0, 0, 0, 1.0f, 0, 0);
    // S = q @ k^T * scale (causal tile skip), per batch
    gemm_bt<EPI_F32SCALE><<<dim3(T / BN, T / BM, Bb), dim3(512), 0, stream>>>(
        qkvb, qkvb + C, nullptr, nullptr, att, C, 3 * C, 3 * C, T,
        (long)T * 3 * C, (long)T * 3 * C, (long)T * T, scale, 1, 0);
    // P = softmax(S) causal, bf16
    softmax_causal<<<dim3(T, Bb), dim3(256), 0, stream>>>(att, pbuf);
    // vt = v^T
    transpose_v<<<dim3(T / 32, C / 32, Bb), dim3(256), 0, stream>>>(qkvb, vt);
    // attn_out = P @ V   (K limited to m0+BM by causality)
    gemm_bt<EPI_BF16><<<dim3(C / BN, T / BM, Bb), dim3(512), 0, stream>>>(
        pbuf, vt, nullptr, nullptr, aout, T, T, T, C, (long)T * T, (long)C * T,
        (long)T * C, 1.0f, 0, 1);
    // x = x + attn_out @ Wo^T + bo
    gemm_bt<EPI_RESID><<<dim3(C / BN, M / BM), dim3(512), 0, stream>>>(
        aout, wo, ob, x, x, C, C, C, C, 0, 0, 0, 1.0f, 0, 0);
    // h = LN2(x)
    ln_kernel<<<dim3(M), dim3(256), 0, stream>>>(x, l2w, l2b, hbuf);
    // ff = gelu(h @ W0^T + b0)
    gemm_bt<EPI_GELU><<<dim3(FF / BN, M / BM), dim3(512), 0, stream>>>(
        hbuf, w0, f0b, nullptr, ffb, C, C, C, FF, 0, 0, 0, 1.0f, 0, 0);
    // x = x + ff @ W3^T + b3
    gemm_bt<EPI_RESID><<<dim3(C / BN, M / BM), dim3(512), 0, stream>>>(
        ffb, w3, f3b, x, x, FF, FF, FF, C, 0, 0, 0, 1.0f, 0, 0);
  }
}

// Round 2
// 4266.948 us; speedup vs baseline: 1.0271x; 1.0271x over previous
//
#include <hip/hip_runtime.h>
#include <hip/hip_bf16.h>
#include <math.h>

// GPT blocks: B=4, T=2048, C=1024, FF=4096, NB=8. Single-head causal attn.
// GEMM: 256x256 tile, BK=64, 8 waves, 4-phase/K-tile pipelined schedule.
// All K-loop LDS reads are opaque inline-asm ds_read_b128 so the compiler's
// waitcnt pass cannot insert vmcnt(0) drains against outstanding
// global_load_lds staging; all waits are manual counted vmcnt + lgkmcnt(0)
// + sched_barrier(0) (rule #18). T2 XOR bank swizzle on global source,
// T5 setprio around MFMA clusters, T1 XCD remap.

typedef __bf16 bf16;
typedef __bf16 bf16x8 __attribute__((ext_vector_type(8)));
typedef __bf16 bf16x4 __attribute__((ext_vector_type(4)));
typedef float f32x4 __attribute__((ext_vector_type(4)));
typedef const __attribute__((address_space(3))) bf16* lds_cp;

#define BM 256
#define BN 256
#define BK 64

__device__ __forceinline__ void async_load16(const void* g, void* l) {
  __builtin_amdgcn_global_load_lds(
      (const __attribute__((address_space(1))) void*)g,
      (__attribute__((address_space(3))) void*)l, 16, 0, 0);
}

constexpr int EPI_BF16 = 0;     // C = bf16(acc + bias)           (bias may be null)
constexpr int EPI_GELU = 1;     // C = bf16(gelu(acc + bias))
constexpr int EPI_RESID = 2;    // C = f32(resid + acc + bias)
constexpr int EPI_F32SCALE = 3; // C = f32(acc * alpha)

// Stage one 128x64 half-tile (2 x global_load_lds 16B per thread).
#define STAGE(S0, S1, LB, HH, JJ, LD)                                \
  do {                                                               \
    const long soff_ = (long)(HH)*128 * (LD) + (long)(JJ)*64;        \
    async_load16((S0) + soff_, (LB) + (HH)*8192);                    \
    async_load16((S1) + soff_, (LB) + (HH)*8192 + 4096);             \
  } while (0)

// Opaque LDS read: compiler cannot see the ds_read, so it inserts no waits.
#define DSR(dst, p) \
  asm volatile("ds_read_b128 %0, %1" : "=v"(dst) : "v"((lds_cp)(p)))

#define VMW(n) asm volatile("s_waitcnt vmcnt(" #n ")" ::: "memory")
#define LGKM0                                        \
  do {                                               \
    asm volatile("s_waitcnt lgkmcnt(0)" ::: "memory"); \
    __builtin_amdgcn_sched_barrier(0);               \
  } while (0)

#define READ_A(MH)                                                   \
  do {                                                               \
    const bf16* pa0_ = sm + bufo + (MH)*8192 + aB + xk0;             \
    const bf16* pa1_ = sm + bufo + (MH)*8192 + aB + xk1;             \
    DSR(a[0][0], pa0_);        DSR(a[0][1], pa1_);                   \
    DSR(a[1][0], pa0_ + 1024); DSR(a[1][1], pa1_ + 1024);            \
    DSR(a[2][0], pa0_ + 2048); DSR(a[2][1], pa1_ + 2048);            \
    DSR(a[3][0], pa0_ + 3072); DSR(a[3][1], pa1_ + 3072);            \
  } while (0)

#define READ_B(DST, NH)                                              \
  do {                                                               \
    const bf16* pb0_ = sm + bufo + 16384 + (NH)*8192 + bB + xk0;     \
    const bf16* pb1_ = sm + bufo + 16384 + (NH)*8192 + bB + xk1;     \
    DSR(DST[0][0], pb0_);        DSR(DST[0][1], pb1_);               \
    DSR(DST[1][0], pb0_ + 1024); DSR(DST[1][1], pb1_ + 1024);        \
  } while (0)

#define MFMA16(MH, NH, BMAT)                                               \
  do {                                                                     \
    __builtin_amdgcn_s_setprio(1);                                         \
    _Pragma("unroll") for (int mi = 0; mi < 4; ++mi)                       \
    _Pragma("unroll") for (int ni = 0; ni < 2; ++ni)                       \
    _Pragma("unroll") for (int ks = 0; ks < 2; ++ks)                       \
      acc[(MH)*4 + mi][(NH)*2 + ni] =                                      \
          __builtin_amdgcn_mfma_f32_16x16x32_bf16(                         \
              a[mi][ks], BMAT[ni][ks], acc[(MH)*4 + mi][(NH)*2 + ni],      \
              0, 0, 0);                                                    \
    __builtin_amdgcn_s_setprio(0);                                         \
    __builtin_amdgcn_sched_barrier(0);                                     \
  } while (0)

// C[M,N] = A[M,K] @ B[N,K]^T ; tiles full (M,N mult of 256, K mult of 64).
// gridDim.y (m-strips) must be a multiple of 8 for the XCD remap.
template <int EPI>
__global__ __launch_bounds__(512, 2) void gemm_bt(
    const bf16* __restrict__ A, const bf16* __restrict__ Bw,
    const float* __restrict__ bias, const float* __restrict__ resid,
    void* __restrict__ Cout, int K, int lda, int ldb, int ldc,
    long batchA, long batchB, long batchC, float alpha,
    int causalSkip, int kLimit) {
  // --- XCD-aware remap: each XCD owns whole m-strips (A reuse in its L2).
  const int nx = gridDim.x;
  const int lin = blockIdx.y * nx + blockIdx.x;
  const int xcd = lin & 7;
  const int tt = lin >> 3;
  const int n_idx = tt % nx;
  const int j_idx = tt / nx;
  const int m0 = (xcd + 8 * j_idx) * BM;
  const int n0 = n_idx * BN;
  if (causalSkip && n0 > m0) return;  // fully-masked score tile
  const int bz = blockIdx.z;
  const bf16* Ab = A + (long)bz * batchA;
  const bf16* Bb = Bw + (long)bz * batchB;
  const int kEnd = kLimit ? ((m0 + BM < K) ? (m0 + BM) : K) : K;
  const int nT = kEnd >> 6;  // K-tiles of 64 (always >= 4 here)

  // [buf:2][A 2half | B 2half][128 rows][64 k] bf16 = 128 KiB
  __shared__ alignas(16) bf16 sm[65536];

  const int tid = threadIdx.x;
  const int wave = tid >> 6;
  const int lane = tid & 63;
  const int wr = wave >> 2;  // 2 m-wave rows: 64 rows in EACH A-half
  const int wc = wave & 3;   // 4 n-wave cols: 32 cols in EACH B-half
  const int l16 = lane & 15;
  const int kq = lane >> 4;

  // --- staging geometry: granule g covers row g>>3, physical k-granule g&7;
  // bank swizzle q = p ^ (row&7) applied on the GLOBAL source address
  // (global_load_lds LDS dest is lane-linear).
  const int row0 = tid >> 3;  // 0..63 (second load adds 64)
  const int q0 = (tid & 7) ^ ((tid >> 3) & 7);
  const bf16* aS0 = Ab + (long)(m0 + row0) * lda + q0 * 8;
  const bf16* aS1 = aS0 + (long)64 * lda;
  const bf16* bS0 = Bb + (long)(n0 + row0) * ldb + q0 * 8;
  const bf16* bS1 = bS0 + (long)64 * ldb;
  bf16* ldsA = sm + wave * 512;            // + buf*32768 + half*8192
  bf16* ldsB = sm + 16384 + wave * 512;

  // --- fragment read offsets: logical granule (ks*4+kq) at row r lives at
  // physical granule ^(r&7); fragment rows = 16*mi + l16 -> r&7 = l16&7.
  const int xk0 = (kq ^ (l16 & 7)) * 8;
  const int xk1 = ((4 + kq) ^ (l16 & 7)) * 8;
  const int aB = (wr * 64 + l16) * 64;
  const int bB = (wc * 32 + l16) * 64;

  f32x4 acc[8][4] = {};
  bf16x8 a[4][2], b0[2][2], b1[2][2];

  // --- prologue: stage tile0 halves in consumption order A0,B0,B1,A1
  STAGE(aS0, aS1, ldsA, 0, 0, lda);
  STAGE(bS0, bS1, ldsB, 0, 0, ldb);
  STAGE(bS0, bS1, ldsB, 1, 0, ldb);
  STAGE(aS0, aS1, ldsA, 1, 0, lda);
  VMW(4);  // A0,B0 landed; B1,A1 in flight
  __builtin_amdgcn_s_barrier();

  for (int t = 0; t < nT; ++t) {
    const unsigned bufo = (t & 1) ? 32768u : 0u;
    bf16* sAn = ldsA + (((t + 1) & 1) ? 32768 : 0);
    bf16* sBn = ldsB + (((t + 1) & 1) ? 32768 : 0);
    const bool pf = (t + 1 < nT);

    // ---- P1 (mh=0, nh=0): reads A0,B0(t); stage A0(t+1)
    READ_A(0);
    READ_B(b0, 0);
    if (pf) {
      STAGE(aS0, aS1, sAn, 0, t + 1, lda);
      VMW(4);  // B1(t) landed
    } else {
      VMW(2);  // tail: B1(t) landed
    }
    __builtin_amdgcn_s_barrier();
    LGKM0;
    MFMA16(0, 0, b0);
    __builtin_amdgcn_s_barrier();

    // ---- P2 (mh=0, nh=1): reads B1(t); stage B0(t+1)
    READ_B(b1, 1);
    if (pf) {
      STAGE(bS0, bS1, sBn, 0, t + 1, ldb);
      VMW(4);  // A1(t) landed
    } else {
      VMW(0);  // tail: A1(t) landed
    }
    __builtin_amdgcn_s_barrier();
    LGKM0;
    MFMA16(0, 1, b1);
    __builtin_amdgcn_s_barrier();

    // ---- P3 (mh=1, nh=1): reads A1(t); stage B1(t+1) (no wait)
    READ_A(1);
    if (pf) STAGE(bS0, bS1, sBn, 1, t + 1, ldb);
    __builtin_amdgcn_s_barrier();
    LGKM0;
    MFMA16(1, 1, b1);
    __builtin_amdgcn_s_barrier();

    // ---- P4 (mh=1, nh=0): no reads (b0 held); stage A1(t+1)
    if (pf) {
      STAGE(aS0, aS1, sAn, 1, t + 1, lda);
      VMW(4);  // A0(t+1),B0(t+1) landed for next P1
    }
    __builtin_amdgcn_s_barrier();
    MFMA16(1, 0, b0);
    __builtin_amdgcn_s_barrier();
  }

  // C/D layout: col = lane&15, row = (lane>>4)*4 + reg  [m89/m91 verified]
  const int laneRow = (lane >> 4) * 4;
#pragma unroll
  for (int nh = 0; nh < 2; ++nh) {
#pragma unroll
    for (int ni = 0; ni < 2; ++ni) {
      const int col = n0 + nh * 128 + wc * 32 + ni * 16 + l16;
      float bv = 0.0f;
      if (EPI != EPI_F32SCALE && bias != nullptr) bv = bias[col];
#pragma unroll
      for (int mh = 0; mh < 2; ++mh) {
#pragma unroll
        for (int mi = 0; mi < 4; ++mi) {
          const int rowb = m0 + mh * 128 + wr * 64 + mi * 16 + laneRow;
          const f32x4 v4 = acc[mh * 4 + mi][nh * 2 + ni];
#pragma unroll
          for (int r = 0; r < 4; ++r) {
            const float v = v4[r];
            const long idx = (long)bz * batchC + (long)(rowb + r) * ldc + col;
            if (EPI == EPI_F32SCALE) {
              ((float*)Cout)[idx] = v * alpha;
            } else if (EPI == EPI_RESID) {
              ((float*)Cout)[idx] = resid[idx] + v + bv;
            } else if (EPI == EPI_GELU) {
              const float u = v + bv;
              const float g = 0.5f * u * (1.0f + erff(u * 0.70710678118654752f));
              ((bf16*)Cout)[idx] = (bf16)g;
            } else {
              ((bf16*)Cout)[idx] = (bf16)(v + bv);
            }
          }
        }
      }
    }
  }
}

// LayerNorm: one block per row of 1024, fp32 in -> bf16 out
__global__ __launch_bounds__(256) void ln_kernel(
    const float* __restrict__ x, const float* __restrict__ w,
    const float* __restrict__ b, bf16* __restrict__ out) {
  const int C = 1024;
  const long row = blockIdx.x;
  const int t = threadIdx.x;
  const float4 v = ((const float4*)(x + row * C))[t];
  float s = v.x + v.y + v.z + v.w;
  float sq = v.x * v.x + v.y * v.y + v.z * v.z + v.w * v.w;
#pragma unroll
  for (int o = 1; o < 64; o <<= 1) {
    s += __shfl_xor(s, o, 64);
    sq += __shfl_xor(sq, o, 64);
  }
  __shared__ float rs[4], rq[4];
  const int wv = t >> 6, ln = t & 63;
  if (!ln) { rs[wv] = s; rq[wv] = sq; }
  __syncthreads();
  s = rs[0] + rs[1] + rs[2] + rs[3];
  sq = rq[0] + rq[1] + rq[2] + rq[3];
  const float mean = s * (1.0f / 1024.0f);
  const float var = sq * (1.0f / 1024.0f) - mean * mean;
  const float rstd = rsqrtf(var + 1e-5f);
  const float4 wv4 = ((const float4*)w)[t];
  const float4 bv4 = ((const float4*)b)[t];
  bf16x4 o = {(bf16)((v.x - mean) * rstd * wv4.x + bv4.x),
              (bf16)((v.y - mean) * rstd * wv4.y + bv4.y),
              (bf16)((v.z - mean) * rstd * wv4.z + bv4.z),
              (bf16)((v.w - mean) * rstd * wv4.w + bv4.w)};
  ((bf16x4*)(out + row * C))[t] = o;
}

// Causal softmax over fp32 scores row (already scaled) -> bf16 P, zeros for s>t
__global__ __launch_bounds__(256) void softmax_causal(
    const float* __restrict__ S, bf16* __restrict__ P) {
  const int T = 2048;
  const int t = blockIdx.x, b = blockIdx.y;
  const long rowoff = ((long)b * T + t) * (long)T;
  const float* row = S + rowoff;
  bf16* prow = P + rowoff;
  const int L = t + 1;
  const int tid = threadIdx.x;
  float vals[8];
  float mx = -1e30f;
#pragma unroll
  for (int i = 0; i < 8; i++) {
    const int idx = tid + i * 256;
    if (idx < L) {
      vals[i] = row[idx];
      mx = fmaxf(mx, vals[i]);
    } else {
      vals[i] = -1e30f;
    }
  }
#pragma unroll
  for (int o = 1; o < 64; o <<= 1) mx = fmaxf(mx, __shfl_xor(mx, o, 64));
  __shared__ float red[4], red2[4];
  const int wv = tid >> 6, ln = tid & 63;
  if (!ln) red[wv] = mx;
  __syncthreads();
  mx = fmaxf(fmaxf(red[0], red[1]), fmaxf(red[2], red[3]));
  float sum = 0.0f;
#pragma unroll
  for (int i = 0; i < 8; i++) {
    const int idx = tid + i * 256;
    const float e = (idx < L) ? __expf(vals[i] - mx) : 0.0f;
    vals[i] = e;
    sum += e;
  }
#pragma unroll
  for (int o = 1; o < 64; o <<= 1) sum += __shfl_xor(sum, o, 64);
  if (!ln) red2[wv] = sum;
  __syncthreads();
  sum = red2[0] + red2[1] + red2[2] + red2[3];
  const float inv = 1.0f / sum;
#pragma unroll
  for (int i = 0; i < 8; i++) prow[tid + i * 256] = (bf16)(vals[i] * inv);
}

// V transpose: qkv[b, s, 2048+c] -> vt[b, c, s]  (bf16)
__global__ __launch_bounds__(256) void transpose_v(
    const bf16* __restrict__ qkv, bf16* __restrict__ vt) {
  const int T = 2048, C3 = 3072, C = 1024, COFF = 2048;
  __shared__ bf16 tile[32][33];
  const int b = blockIdx.z;
  const int s0 = blockIdx.x * 32, c0 = blockIdx.y * 32;
  const int tx = threadIdx.x & 31, ty0 = threadIdx.x >> 5;
#pragma unroll
  for (int j = 0; j < 4; j++) {
    const int ty = ty0 + j * 8;
    tile[ty][tx] = qkv[((long)b * T + s0 + ty) * C3 + COFF + c0 + tx];
  }
  __syncthreads();
#pragma unroll
  for (int j = 0; j < 4; j++) {
    const int ty = ty0 + j * 8;
    vt[(long)b * C * T + (long)(c0 + ty) * T + s0 + tx] = tile[tx][ty];
  }
}

__global__ void f2bf_kernel(const float* __restrict__ in,
                            bf16* __restrict__ out, long n4) {
  const long i = (long)blockIdx.x * blockDim.x + threadIdx.x;
  if (i < n4) {
    const float4 v = ((const float4*)in)[i];
    bf16x4 o = {(bf16)v.x, (bf16)v.y, (bf16)v.z, (bf16)v.w};
    ((bf16x4*)out)[i] = o;
  }
}

extern "C" void kernel_launch(void* const* d_in, const int* in_sizes, int n_in,
                              void* d_out, int out_size, void* d_ws,
                              size_t ws_size, hipStream_t stream) {
  const int Bb = 4, T = 2048, C = 1024, FF = 4096, NB = 8;
  const int M = Bb * T;  // 8192
  const float* x_in = (const float*)d_in[0];
  const float* ln1_w = (const float*)d_in[1];
  const float* ln1_b = (const float*)d_in[2];
  const float* qkv_w = (const float*)d_in[3];
  const float* qkv_b = (const float*)d_in[4];
  const float* out_w = (const float*)d_in[5];
  const float* out_b = (const float*)d_in[6];
  const float* ln2_w = (const float*)d_in[7];
  const float* ln2_b = (const float*)d_in[8];
  const float* ff0_w = (const float*)d_in[9];
  const float* ff0_b = (const float*)d_in[10];
  const float* ff3_w = (const float*)d_in[11];
  const float* ff3_b = (const float*)d_in[12];
  float* x = (float*)d_out;  // fp32 residual stream lives in d_out

  char* p = (char*)d_ws;
  auto alloc = [&](size_t bytes) {
    char* r = p;
    p += (bytes + 255) & ~(size_t)255;
    return r;
  };
  bf16* wqkv = (bf16*)alloc((size_t)NB * 3 * C * C * 2);
  bf16* wout = (bf16*)alloc((size_t)NB * C * C * 2);
  bf16* wff0 = (bf16*)alloc((size_t)NB * FF * C * 2);
  bf16* wff3 = (bf16*)alloc((size_t)NB * C * FF * 2);
  bf16* hbuf = (bf16*)alloc((size_t)M * C * 2);
  bf16* qkvb = (bf16*)alloc((size_t)M * 3 * C * 2);
  float* att = (float*)alloc((size_t)Bb * T * T * 4);
  bf16* pbuf = (bf16*)alloc((size_t)Bb * T * T * 2);
  bf16* vt = (bf16*)alloc((size_t)Bb * C * T * 2);
  bf16* aout = (bf16*)alloc((size_t)M * C * 2);
  bf16* ffb = (bf16*)att;  // FF intermediate aliases scores buffer (phase-disjoint)

  auto conv = [&](const float* src, bf16* dst, long n) {
    const long n4 = n / 4;
    f2bf_kernel<<<dim3((unsigned)((n4 + 255) / 256)), dim3(256), 0, stream>>>(
        src, dst, n4);
  };
  conv(qkv_w, wqkv, (long)NB * 3 * C * C);
  conv(out_w, wout, (long)NB * C * C);
  conv(ff0_w, wff0, (long)NB * FF * C);
  conv(ff3_w, wff3, (long)NB * C * FF);

  hipMemcpyAsync(x, x_in, (size_t)M * C * 4, hipMemcpyDeviceToDevice, stream);

  const float scale = 1.0f / 32.0f;  // 1/sqrt(C)

  for (int blk = 0; blk < NB; blk++) {
    const bf16* wq = wqkv + (long)blk * 3 * C * C;
    const bf16* wo = wout + (long)blk * C * C;
    const bf16* w0 = wff0 + (long)blk * FF * C;
    const bf16* w3 = wff3 + (long)blk * C * FF;
    const float* l1w = ln1_w + blk * C;
    const float* l1b = ln1_b + blk * C;
    const float* l2w = ln2_w + blk * C;
    const float* l2b = ln2_b + blk * C;
    const float* qb = qkv_b + blk * 3 * C;
    const float* ob = out_b + blk * C;
    const float* f0b = ff0_b + blk * FF;
    const float* f3b = ff3_b + blk * C;

    // h = LN1(x)
    ln_kernel<<<dim3(M), dim3(256), 0, stream>>>(x, l1w, l1b, hbuf);
    // qkv = h @ Wqkv^T + b
    gemm_bt<EPI_BF16><<<dim3(3 * C / BN, M / BM), dim3(512), 0, stream>>>(
        hbuf, wq, qb, nullptr, qkvb, C, C, C, 3 * C, 0, 0, 0, 1.0f, 0, 0);
    // S = q @ k^T * scale (causal tile skip), per batch
    gemm_bt<EPI_F32SCALE><<<dim3(T / BN, T / BM, Bb), dim3(512), 0, stream>>>(
        qkvb, qkvb + C, nullptr, nullptr, att, C, 3 * C, 3 * C, T,
        (long)T * 3 * C, (long)T * 3 * C, (long)T * T, scale, 1, 0);
    // P = softmax(S) causal, bf16
    softmax_causal<<<dim3(T, Bb), dim3(256), 0, stream>>>(att, pbuf);
    // vt = v^T
    transpose_v<<<dim3(T / 32, C / 32, Bb), dim3(256), 0, stream>>>(qkvb, vt);
    // attn_out = P @ V   (K limited to m0+BM by causality)
    gemm_bt<EPI_BF16><<<dim3(C / BN, T / BM, Bb), dim3(512), 0, stream>>>(
        pbuf, vt, nullptr, nullptr, aout, T, T, T, C, (long)T * T, (long)C * T,
        (long)T * C, 1.0f, 0, 1);
    // x = x + attn_out @ Wo^T + bo
    gemm_bt<EPI_RESID><<<dim3(C / BN, M / BM), dim3(512), 0, stream>>>(
        aout, wo, ob, x, x, C, C, C, C, 0, 0, 0, 1.0f, 0, 0);
    // h = LN2(x)
    ln_kernel<<<dim3(M), dim3(256), 0, stream>>>(x, l2w, l2b, hbuf);
    // ff = gelu(h @ W0^T + b0)
    gemm_bt<EPI_GELU><<<dim3(FF / BN, M / BM), dim3(512), 0, stream>>>(
        hbuf, w0, f0b, nullptr, ffb, C, C, C, FF, 0, 0, 0, 1.0f, 0, 0);
    // x = x + ff @ W3^T + b3
    gemm_bt<EPI_RESID><<<dim3(C / BN, M / BM), dim3(512), 0, stream>>>(
        ffb, w3, f3b, x, x, FF, FF, FF, C, 0, 0, 0, 1.0f, 0, 0);
  }
}